// Round 1
// baseline (1943.197 us; speedup 1.0000x reference)
//
#include <hip/hip_runtime.h>
#include <math.h>

// SpikeMixtralDecoderLayer on MI355X (gfx950)
// B=1, S=2048, H=2048, NH=32, HD=64, NKV=8, E=8, TOPK=2, F=4096
//
// Pipeline:
//  1) convert weights fp32->bf16 (attention weights split hi/lo for precision)
//  2) rmsnorm1 -> x (split bf16)
//  3) QKV split-GEMM -> qkv fp32
//  4) RoPE (double-precision angle table) -> q,k split; v split; v transposed
//  5) split flash attention -> o (split bf16)
//  6) Wo split-GEMM + residual -> hidden fp32
//  7) rmsnorm2 -> xm fp32 (router) + bf16 (MoE)
//  8) router top-2 (fp32) -> expert-sorted, 128-padded token slots
//  9) MoE: h13 = xg@[w1;w3]^T (bf16 GEMM), hprod = silu(h1)*h3,
//     out = hidden + sum atomicAdd( w * hprod@w2^T )

using u16 = unsigned short;
using u32 = unsigned int;
typedef __attribute__((ext_vector_type(8))) short short8;
typedef __attribute__((ext_vector_type(4))) float f32x4;

__device__ __forceinline__ u16 f2bf(float f) {
  union { float f; u32 u; } v; v.f = f;
  u32 r = v.u + 0x7FFFu + ((v.u >> 16) & 1u);
  return (u16)(r >> 16);
}
__device__ __forceinline__ float bf2f(u16 h) {
  union { float f; u32 u; } v; v.u = ((u32)h) << 16; return v.f;
}
__device__ __forceinline__ short8 ld8(const u16* p) { return *(const short8*)p; }

__device__ __forceinline__ void gload16(const u16* g, u16* l) {
  __builtin_amdgcn_global_load_lds((const __attribute__((address_space(1))) u32*)g,
                                   (__attribute__((address_space(3))) u32*)l, 16, 0, 0);
}

// ---------------- weight conversion ----------------

__global__ __launch_bounds__(256) void conv_split_k(const float* __restrict__ src,
                                                    u16* __restrict__ hi, u16* __restrict__ lo) {
  size_t g = ((size_t)blockIdx.x * 256 + threadIdx.x) * 8;
  float4 a = *(const float4*)(src + g), b = *(const float4*)(src + g + 4);
  float x[8] = {a.x, a.y, a.z, a.w, b.x, b.y, b.z, b.w};
  short8 h, l;
#pragma unroll
  for (int i = 0; i < 8; i++) {
    u16 hh = f2bf(x[i]);
    h[i] = (short)hh;
    l[i] = (short)f2bf(x[i] - bf2f(hh));
  }
  *(short8*)(hi + g) = h;
  *(short8*)(lo + g) = l;
}

__global__ __launch_bounds__(256) void conv_wqkv_k(const float* __restrict__ wq,
                                                   const float* __restrict__ wk,
                                                   const float* __restrict__ wv,
                                                   u16* __restrict__ hi, u16* __restrict__ lo) {
  size_t g = ((size_t)blockIdx.x * 256 + threadIdx.x) * 8;  // [3072][2048]
  int row = (int)(g >> 11);
  int col = (int)(g & 2047);
  const float* src;
  if (row < 2048)      src = wq + ((size_t)row << 11) + col;
  else if (row < 2560) src = wk + ((size_t)(row - 2048) << 11) + col;
  else                 src = wv + ((size_t)(row - 2560) << 11) + col;
  float4 a = *(const float4*)src, b = *(const float4*)(src + 4);
  float x[8] = {a.x, a.y, a.z, a.w, b.x, b.y, b.z, b.w};
  short8 h, l;
#pragma unroll
  for (int i = 0; i < 8; i++) {
    u16 hh = f2bf(x[i]);
    h[i] = (short)hh;
    l[i] = (short)f2bf(x[i] - bf2f(hh));
  }
  *(short8*)(hi + g) = h;
  *(short8*)(lo + g) = l;
}

__global__ __launch_bounds__(256) void conv_w13_k(const float* __restrict__ w1,
                                                  const float* __restrict__ w3,
                                                  u16* __restrict__ dst) {
  size_t g = ((size_t)blockIdx.x * 256 + threadIdx.x) * 8;  // [8][8192][2048]
  int e = (int)(g >> 24);
  int r = (int)((g >> 11) & 8191);
  int col = (int)(g & 2047);
  const float* src = (r < 4096) ? (w1 + (size_t)e * 8388608 + ((size_t)r << 11) + col)
                                : (w3 + (size_t)e * 8388608 + ((size_t)(r - 4096) << 11) + col);
  float4 a = *(const float4*)src, b = *(const float4*)(src + 4);
  float x[8] = {a.x, a.y, a.z, a.w, b.x, b.y, b.z, b.w};
  short8 h;
#pragma unroll
  for (int i = 0; i < 8; i++) h[i] = (short)f2bf(x[i]);
  *(short8*)(dst + g) = h;
}

__global__ __launch_bounds__(256) void conv_bf_k(const float* __restrict__ src, u16* __restrict__ dst) {
  size_t g = ((size_t)blockIdx.x * 256 + threadIdx.x) * 8;
  float4 a = *(const float4*)(src + g), b = *(const float4*)(src + g + 4);
  float x[8] = {a.x, a.y, a.z, a.w, b.x, b.y, b.z, b.w};
  short8 h;
#pragma unroll
  for (int i = 0; i < 8; i++) h[i] = (short)f2bf(x[i]);
  *(short8*)(dst + g) = h;
}

// ---------------- rmsnorm ----------------

__global__ __launch_bounds__(256) void rmsnorm_k(const float* __restrict__ in, const float* __restrict__ w,
                                                 u16* __restrict__ ohi, u16* __restrict__ olo,
                                                 float* __restrict__ of, u16* __restrict__ obf) {
  int row = blockIdx.x, tid = threadIdx.x;
  const float* r = in + (size_t)row * 2048;
  float4 a = *(const float4*)&r[tid * 8];
  float4 b = *(const float4*)&r[tid * 8 + 4];
  float x[8] = {a.x, a.y, a.z, a.w, b.x, b.y, b.z, b.w};
  float ss = 0.f;
#pragma unroll
  for (int i = 0; i < 8; i++) ss += x[i] * x[i];
#pragma unroll
  for (int off = 32; off > 0; off >>= 1) ss += __shfl_xor(ss, off);
  __shared__ float red[4];
  if ((tid & 63) == 0) red[tid >> 6] = ss;
  __syncthreads();
  float tot = red[0] + red[1] + red[2] + red[3];
  float rms = rsqrtf(tot * (1.0f / 2048.0f) + 1e-5f);
  float4 wa = *(const float4*)&w[tid * 8];
  float4 wb = *(const float4*)&w[tid * 8 + 4];
  float wv[8] = {wa.x, wa.y, wa.z, wa.w, wb.x, wb.y, wb.z, wb.w};
  size_t o = (size_t)row * 2048 + tid * 8;
#pragma unroll
  for (int i = 0; i < 8; i++) {
    float y = x[i] * rms * wv[i];
    if (ohi) {
      u16 hh = f2bf(y);
      ohi[o + i] = hh;
      olo[o + i] = f2bf(y - bf2f(hh));
    }
    if (of) of[o + i] = y;
    if (obf) obf[o + i] = f2bf(y);
  }
}

// ---------------- GEMM (m97-style, optional hi/lo split, 4 epilogues) ----------------
// C[m][n] = sum_k A[m][k]*B[n][k]   A:[M][K] bf16, B:[N][K] bf16 (row major)
// EPI 0: f32 out   1: resid+f32 out   2: bf16 out   3: MoE scaled atomicAdd

template <int EPI, bool SPLIT>
__global__ __launch_bounds__(256, 2) void gemm_k(
    const u16* __restrict__ Ah, const u16* __restrict__ Al,
    const u16* __restrict__ Bh, const u16* __restrict__ Bl,
    int K, int ldc,
    float* __restrict__ outF, u16* __restrict__ outB,
    const float* __restrict__ resid,
    const int* __restrict__ mbase, long eNK,
    const int* __restrict__ tokof, const float* __restrict__ wgtof) {
  __shared__ __align__(16) u16 lA[128 * 32];
  __shared__ __align__(16) u16 lB[128 * 32];
  __shared__ __align__(16) u16 lAl[SPLIT ? 128 * 32 : 8];
  __shared__ __align__(16) u16 lBl[SPLIT ? 128 * 32 : 8];
  const int tid = threadIdx.x;
  const int lane = tid & 63;
  const int wv = tid >> 6, wr = wv >> 1, wc = wv & 1;
  const int fr = lane & 15, fq = lane >> 4;
  int m0 = blockIdx.y * 128;
  const int n0 = blockIdx.x * 128;
  const u16* bh = Bh;
  const u16* bl = Bl;
  if (mbase) {
    if (m0 >= mbase[8]) return;
    int e = 0;
#pragma unroll
    for (int i = 1; i < 8; i++)
      if (m0 >= mbase[i]) e = i;
    bh = Bh + (size_t)e * eNK;
    if (SPLIT) bl = Bl + (size_t)e * eNK;
  }
  f32x4 acc[4][4];
#pragma unroll
  for (int m = 0; m < 4; m++)
#pragma unroll
    for (int n = 0; n < 4; n++) acc[m][n] = f32x4{0.f, 0.f, 0.f, 0.f};

  const int srow = tid >> 2, skc = (tid & 3) * 8;
  const int wb = (tid & ~63) * 8;
  const size_t rA0 = (size_t)(m0 + srow) * K + skc;
  const size_t rA1 = (size_t)(m0 + 64 + srow) * K + skc;
  const size_t rB0 = (size_t)(n0 + srow) * K + skc;
  const size_t rB1 = (size_t)(n0 + 64 + srow) * K + skc;

  for (int k0 = 0; k0 < K; k0 += 32) {
    gload16(Ah + rA0 + k0, lA + wb);
    gload16(Ah + rA1 + k0, lA + 2048 + wb);
    gload16(bh + rB0 + k0, lB + wb);
    gload16(bh + rB1 + k0, lB + 2048 + wb);
    if (SPLIT) {
      gload16(Al + rA0 + k0, lAl + wb);
      gload16(Al + rA1 + k0, lAl + 2048 + wb);
      gload16(bl + rB0 + k0, lBl + wb);
      gload16(bl + rB1 + k0, lBl + 2048 + wb);
    }
    __syncthreads();
    short8 a[4], b[4], a2[4], b2[4];
#pragma unroll
    for (int m = 0; m < 4; m++) a[m] = *(const short8*)&lA[(wr * 64 + m * 16 + fr) * 32 + fq * 8];
#pragma unroll
    for (int n = 0; n < 4; n++) b[n] = *(const short8*)&lB[(wc * 64 + n * 16 + fr) * 32 + fq * 8];
    if (SPLIT) {
#pragma unroll
      for (int m = 0; m < 4; m++) a2[m] = *(const short8*)&lAl[(wr * 64 + m * 16 + fr) * 32 + fq * 8];
#pragma unroll
      for (int n = 0; n < 4; n++) b2[n] = *(const short8*)&lBl[(wc * 64 + n * 16 + fr) * 32 + fq * 8];
    }
#pragma unroll
    for (int m = 0; m < 4; m++)
#pragma unroll
      for (int n = 0; n < 4; n++) {
        acc[m][n] = __builtin_amdgcn_mfma_f32_16x16x32_bf16(a[m], b[n], acc[m][n], 0, 0, 0);
        if (SPLIT) {
          acc[m][n] = __builtin_amdgcn_mfma_f32_16x16x32_bf16(a[m], b2[n], acc[m][n], 0, 0, 0);
          acc[m][n] = __builtin_amdgcn_mfma_f32_16x16x32_bf16(a2[m], b[n], acc[m][n], 0, 0, 0);
        }
      }
    __syncthreads();
  }
#pragma unroll
  for (int m = 0; m < 4; m++)
#pragma unroll
    for (int n = 0; n < 4; n++)
#pragma unroll
      for (int j = 0; j < 4; j++) {
        int row = m0 + wr * 64 + m * 16 + fq * 4 + j;
        int col = n0 + wc * 64 + n * 16 + fr;
        float v = acc[m][n][j];
        if constexpr (EPI == 0) {
          outF[(size_t)row * ldc + col] = v;
        } else if constexpr (EPI == 1) {
          outF[(size_t)row * ldc + col] = resid[(size_t)row * ldc + col] + v;
        } else if constexpr (EPI == 2) {
          outB[(size_t)row * ldc + col] = f2bf(v);
        } else {
          int t = tokof[row];
          if (t >= 0) atomicAdd(outF + (size_t)t * 2048 + col, wgtof[row] * v);
        }
      }
}

// ---------------- RoPE ----------------

__global__ __launch_bounds__(256) void rope_tab_k(float* __restrict__ ctab, float* __restrict__ stab) {
  int i = blockIdx.x * 256 + threadIdx.x;  // 2048*32
  int s = i >> 5, d = i & 31;
  double freq = pow(1.0e6, -(double)d / 32.0);
  double a = (double)s * freq;
  ctab[i] = (float)cos(a);
  stab[i] = (float)sin(a);
}

__global__ __launch_bounds__(64) void rope_k(const float* __restrict__ qkv,
                                             const float* __restrict__ ctab, const float* __restrict__ stab,
                                             u16* __restrict__ qh, u16* __restrict__ ql,
                                             u16* __restrict__ kh, u16* __restrict__ kl,
                                             u16* __restrict__ vh, u16* __restrict__ vl) {
  int s = blockIdx.x, slot = blockIdx.y, d = threadIdx.x;
  const float* row = qkv + (size_t)s * 3072;
  if (slot < 40) {
    float x = (slot < 32) ? row[slot * 64 + d] : row[2048 + (slot - 32) * 64 + d];
    float pr = __shfl_xor(x, 32);
    float c = ctab[s * 32 + (d & 31)], sn = stab[s * 32 + (d & 31)];
    float v = (d < 32) ? (x * c - pr * sn) : (x * c + pr * sn);
    u16 hh = f2bf(v);
    if (slot < 32) {
      size_t o = (size_t)s * 2048 + slot * 64 + d;
      qh[o] = hh; ql[o] = f2bf(v - bf2f(hh));
    } else {
      size_t o = (size_t)s * 512 + (slot - 32) * 64 + d;
      kh[o] = hh; kl[o] = f2bf(v - bf2f(hh));
    }
  } else {
    int kvh = slot - 40;
    float x = row[2560 + kvh * 64 + d];
    u16 hh = f2bf(x);
    size_t o = (size_t)s * 512 + kvh * 64 + d;
    vh[o] = hh; vl[o] = f2bf(x - bf2f(hh));
  }
}

// transpose V: [s][kvh][64] -> [kvh][64][s]
__global__ __launch_bounds__(256) void vtrans_k(const u16* __restrict__ vh, const u16* __restrict__ vl,
                                                u16* __restrict__ vth, u16* __restrict__ vtl) {
  __shared__ u16 th[64][72];
  __shared__ u16 tl[64][72];
  int s0 = blockIdx.x * 64, kvh = blockIdx.y;
  int tx = threadIdx.x & 63, ty = threadIdx.x >> 6;
  for (int r = ty; r < 64; r += 4) {
    th[r][tx] = vh[(size_t)(s0 + r) * 512 + kvh * 64 + tx];
    tl[r][tx] = vl[(size_t)(s0 + r) * 512 + kvh * 64 + tx];
  }
  __syncthreads();
  for (int r = ty; r < 64; r += 4) {
    vth[(size_t)(kvh * 64 + r) * 2048 + s0 + tx] = th[tx][r];
    vtl[(size_t)(kvh * 64 + r) * 2048 + s0 + tx] = tl[tx][r];
  }
}

// ---------------- split flash attention (1 wave / 16 q-rows) ----------------

__global__ __launch_bounds__(64) void attn_k(const u16* __restrict__ qh_, const u16* __restrict__ ql_,
                                             const u16* __restrict__ kh_, const u16* __restrict__ kl_,
                                             const u16* __restrict__ vth_, const u16* __restrict__ vtl_,
                                             u16* __restrict__ oh_, u16* __restrict__ ol_) {
  __shared__ __align__(16) u16 Ph[16 * 32];
  __shared__ __align__(16) u16 Pl[16 * 32];
  const int l = threadIdx.x;
  const int q0 = blockIdx.x * 16;
  const int h = blockIdx.y;
  const int kvh = h & 7;
  const int fr = l & 15, fq = l >> 4;

  short8 qfh[2], qfl[2];
#pragma unroll
  for (int c = 0; c < 2; c++) {
    size_t o = (size_t)(q0 + fr) * 2048 + h * 64 + c * 32 + fq * 8;
    qfh[c] = ld8(qh_ + o);
    qfl[c] = ld8(ql_ + o);
  }
  float mrun[4], lrun[4];
  f32x4 oacc[4];
#pragma unroll
  for (int j = 0; j < 4; j++) { mrun[j] = -1e30f; lrun[j] = 0.f; }
#pragma unroll
  for (int d0 = 0; d0 < 4; d0++) oacc[d0] = f32x4{0.f, 0.f, 0.f, 0.f};

  const int nt = (q0 + 15) / 32 + 1;
  for (int t = 0; t < nt; ++t) {
    const int kv0 = t * 32;
    f32x4 s[2];
#pragma unroll
    for (int f = 0; f < 2; f++) {
      s[f] = f32x4{0.f, 0.f, 0.f, 0.f};
#pragma unroll
      for (int c = 0; c < 2; c++) {
        size_t o = (size_t)(kv0 + f * 16 + fr) * 512 + kvh * 64 + c * 32 + fq * 8;
        short8 kfh = ld8(kh_ + o);
        short8 kfl = ld8(kl_ + o);
        s[f] = __builtin_amdgcn_mfma_f32_16x16x32_bf16(qfh[c], kfh, s[f], 0, 0, 0);
        s[f] = __builtin_amdgcn_mfma_f32_16x16x32_bf16(qfh[c], kfl, s[f], 0, 0, 0);
        s[f] = __builtin_amdgcn_mfma_f32_16x16x32_bf16(qfl[c], kfh, s[f], 0, 0, 0);
      }
    }
    // scale + causal mask
#pragma unroll
    for (int f = 0; f < 2; f++)
#pragma unroll
      for (int j = 0; j < 4; j++) {
        int row = q0 + fq * 4 + j;
        int col = kv0 + f * 16 + fr;
        float v = s[f][j] * 0.125f;
        s[f][j] = (col <= row) ? v : -1e30f;
      }
    // online softmax
    float p0[4], p1[4];
#pragma unroll
    for (int j = 0; j < 4; j++) {
      float tm = fmaxf(s[0][j], s[1][j]);
      tm = fmaxf(tm, __shfl_xor(tm, 1));
      tm = fmaxf(tm, __shfl_xor(tm, 2));
      tm = fmaxf(tm, __shfl_xor(tm, 4));
      tm = fmaxf(tm, __shfl_xor(tm, 8));
      float nm = fmaxf(mrun[j], tm);
      float sc = expf(mrun[j] - nm);
      float a0 = expf(s[0][j] - nm);
      float a1 = expf(s[1][j] - nm);
      float rs = a0 + a1;
      rs += __shfl_xor(rs, 1);
      rs += __shfl_xor(rs, 2);
      rs += __shfl_xor(rs, 4);
      rs += __shfl_xor(rs, 8);
      lrun[j] = lrun[j] * sc + rs;
      mrun[j] = nm;
#pragma unroll
      for (int d0 = 0; d0 < 4; d0++) oacc[d0][j] *= sc;
      p0[j] = a0; p1[j] = a1;
    }
    // write P (split) to LDS
#pragma unroll
    for (int j = 0; j < 4; j++) {
      int row = fq * 4 + j;
      u16 h0 = f2bf(p0[j]);
      Ph[row * 32 + fr] = h0;
      Pl[row * 32 + fr] = f2bf(p0[j] - bf2f(h0));
      u16 h1 = f2bf(p1[j]);
      Ph[row * 32 + 16 + fr] = h1;
      Pl[row * 32 + 16 + fr] = f2bf(p1[j] - bf2f(h1));
    }
    __syncthreads();
    short8 pa = *(const short8*)&Ph[fr * 32 + fq * 8];
    short8 pal = *(const short8*)&Pl[fr * 32 + fq * 8];
#pragma unroll
    for (int d0 = 0; d0 < 4; d0++) {
      size_t o = (size_t)(kvh * 64 + d0 * 16 + fr) * 2048 + kv0 + fq * 8;
      short8 vh = ld8(vth_ + o);
      short8 vl = ld8(vtl_ + o);
      oacc[d0] = __builtin_amdgcn_mfma_f32_16x16x32_bf16(pa, vh, oacc[d0], 0, 0, 0);
      oacc[d0] = __builtin_amdgcn_mfma_f32_16x16x32_bf16(pa, vl, oacc[d0], 0, 0, 0);
      oacc[d0] = __builtin_amdgcn_mfma_f32_16x16x32_bf16(pal, vh, oacc[d0], 0, 0, 0);
    }
    __syncthreads();
  }
  // write o (split)
#pragma unroll
  for (int d0 = 0; d0 < 4; d0++)
#pragma unroll
    for (int j = 0; j < 4; j++) {
      float v = oacc[d0][j] / lrun[j];
      int srow = q0 + fq * 4 + j;
      int col = h * 64 + d0 * 16 + fr;
      u16 hh = f2bf(v);
      oh_[(size_t)srow * 2048 + col] = hh;
      ol_[(size_t)srow * 2048 + col] = f2bf(v - bf2f(hh));
    }
}

// ---------------- MoE routing ----------------

__global__ void moe_init_k(int* cnt, int* fill, int* tokof) {
  int i = blockIdx.x * 256 + threadIdx.x;
  if (i < 8) { cnt[i] = 0; fill[i] = 0; }
  if (i < 5120) tokof[i] = -1;
}

__global__ __launch_bounds__(64) void router_k(const float* __restrict__ xm, const float* __restrict__ gw,
                                               int* __restrict__ sel, float* __restrict__ topw,
                                               int* __restrict__ cnt) {
  int t = blockIdx.x, lane = threadIdx.x;
  const float* xr = xm + (size_t)t * 2048;
  float xv[32];
#pragma unroll
  for (int k = 0; k < 32; k++) xv[k] = xr[k * 64 + lane];
  float lg[8];
#pragma unroll
  for (int e = 0; e < 8; e++) {
    const float* g = gw + e * 2048;
    float p = 0.f;
#pragma unroll
    for (int k = 0; k < 32; k++) p = fmaf(xv[k], g[k * 64 + lane], p);
#pragma unroll
    for (int off = 32; off > 0; off >>= 1) p += __shfl_xor(p, off);
    lg[e] = p;
  }
  if (lane == 0) {
    float mx = lg[0];
#pragma unroll
    for (int e = 1; e < 8; e++) mx = fmaxf(mx, lg[e]);
    float ex[8];
#pragma unroll
    for (int e = 0; e < 8; e++) ex[e] = expf(lg[e] - mx);
    int b0 = 0;
#pragma unroll
    for (int e = 1; e < 8; e++)
      if (ex[e] > ex[b0]) b0 = e;
    int b1 = (b0 == 0) ? 1 : 0;
#pragma unroll
    for (int e = 0; e < 8; e++)
      if (e != b0 && ex[e] > ex[b1]) b1 = e;
    float w0 = ex[b0] / (ex[b0] + ex[b1]);
    sel[t * 2] = b0; sel[t * 2 + 1] = b1;
    topw[t * 2] = w0; topw[t * 2 + 1] = 1.f - w0;
    atomicAdd(cnt + b0, 1);
    atomicAdd(cnt + b1, 1);
  }
}

__global__ void moe_base_k(const int* cnt, int* mbase) {
  if (threadIdx.x == 0 && blockIdx.x == 0) {
    int b = 0;
    for (int e = 0; e < 8; e++) { mbase[e] = b; b += (cnt[e] + 127) & ~127; }
    mbase[8] = b;
  }
}

__global__ void slot_assign_k(const int* __restrict__ sel, const float* __restrict__ topw,
                              const int* __restrict__ mbase, int* __restrict__ fill,
                              int* __restrict__ tokof, float* __restrict__ wgtof) {
  int t = blockIdx.x * 256 + threadIdx.x;
  if (t >= 2048) return;
#pragma unroll
  for (int k = 0; k < 2; k++) {
    int e = sel[t * 2 + k];
    int pos = atomicAdd(&fill[e], 1);
    int slot = mbase[e] + pos;
    tokof[slot] = t;
    wgtof[slot] = topw[t * 2 + k];
  }
}

__global__ __launch_bounds__(256) void gather_k(const int* __restrict__ tokof, const u16* __restrict__ xmbf,
                                                u16* __restrict__ xg) {
  int slot = blockIdx.x;
  int t = tokof[slot];
  short8 v = {0, 0, 0, 0, 0, 0, 0, 0};
  if (t >= 0) v = *(const short8*)(xmbf + (size_t)t * 2048 + threadIdx.x * 8);
  *(short8*)(xg + (size_t)slot * 2048 + threadIdx.x * 8) = v;
}

__global__ __launch_bounds__(256) void silu_k(const u16* __restrict__ h13, u16* __restrict__ hpr) {
  size_t g = ((size_t)blockIdx.x * 256 + threadIdx.x) * 8;
  int slot = (int)(g >> 12);
  int f = (int)(g & 4095);
  const u16* p1 = h13 + (size_t)slot * 8192 + f;
  const u16* p3 = p1 + 4096;
  short8 a = *(const short8*)p1;
  short8 b = *(const short8*)p3;
  short8 r;
#pragma unroll
  for (int i = 0; i < 8; i++) {
    float x = bf2f((u16)a[i]);
    float y = bf2f((u16)b[i]);
    float s = x / (1.f + expf(-x));
    r[i] = (short)f2bf(s * y);
  }
  *(short8*)(hpr + (size_t)slot * 4096 + f) = r;
}

// ---------------- launch ----------------

extern "C" void kernel_launch(void* const* d_in, const int* in_sizes, int n_in,
                              void* d_out, int out_size, void* d_ws, size_t ws_size,
                              hipStream_t stream) {
  (void)in_sizes; (void)n_in; (void)out_size; (void)ws_size;
  const float* hidden = (const float*)d_in[0];
  const float* ln1 = (const float*)d_in[1];
  const float* ln2 = (const float*)d_in[2];
  const float* wq = (const float*)d_in[3];
  const float* wk = (const float*)d_in[4];
  const float* wv = (const float*)d_in[5];
  const float* wo = (const float*)d_in[6];
  const float* gw = (const float*)d_in[7];
  const float* w1 = (const float*)d_in[8];
  const float* w2 = (const float*)d_in[9];
  const float* w3 = (const float*)d_in[10];
  float* out = (float*)d_out;

  char* base = (char*)d_ws;
  size_t off = 0;
  auto alloc = [&](size_t bytes) -> void* {
    off = (off + 255) & ~(size_t)255;
    void* p = base + off;
    off += bytes;
    return p;
  };
  u16* wqkv_hi = (u16*)alloc(3072UL * 2048 * 2);
  u16* wqkv_lo = (u16*)alloc(3072UL * 2048 * 2);
  u16* wo_hi = (u16*)alloc(2048UL * 2048 * 2);
  u16* wo_lo = (u16*)alloc(2048UL * 2048 * 2);
  u16* w13b = (u16*)alloc(8UL * 8192 * 2048 * 2);
  u16* w2b = (u16*)alloc(8UL * 2048 * 4096 * 2);
  u16* x_hi = (u16*)alloc(2048UL * 2048 * 2);
  u16* x_lo = (u16*)alloc(2048UL * 2048 * 2);
  float* qkvf = (float*)alloc(2048UL * 3072 * 4);
  u16* q_hi = (u16*)alloc(2048UL * 2048 * 2);
  u16* q_lo = (u16*)alloc(2048UL * 2048 * 2);
  u16* k_hi = (u16*)alloc(2048UL * 512 * 2);
  u16* k_lo = (u16*)alloc(2048UL * 512 * 2);
  u16* v_hi = (u16*)alloc(2048UL * 512 * 2);
  u16* v_lo = (u16*)alloc(2048UL * 512 * 2);
  u16* vth = (u16*)alloc(8UL * 64 * 2048 * 2);
  u16* vtl = (u16*)alloc(8UL * 64 * 2048 * 2);
  u16* o_hi = (u16*)alloc(2048UL * 2048 * 2);
  u16* o_lo = (u16*)alloc(2048UL * 2048 * 2);
  float* hidf = (float*)alloc(2048UL * 2048 * 4);
  float* xmf = (float*)alloc(2048UL * 2048 * 4);
  u16* xmbf = (u16*)alloc(2048UL * 2048 * 2);
  float* ctab = (float*)alloc(2048UL * 32 * 4);
  float* stab = (float*)alloc(2048UL * 32 * 4);
  int* sel = (int*)alloc(2048UL * 2 * 4);
  float* topw = (float*)alloc(2048UL * 2 * 4);
  int* cnt = (int*)alloc(32);
  int* fill = (int*)alloc(32);
  int* mbase = (int*)alloc(64);
  int* tokof = (int*)alloc(5120UL * 4);
  float* wgtof = (float*)alloc(5120UL * 4);
  u16* xg = (u16*)alloc(5120UL * 2048 * 2);
  u16* h13 = (u16*)alloc(5120UL * 8192 * 2);
  u16* hpr = (u16*)alloc(5120UL * 4096 * 2);

  // weight conversion
  conv_wqkv_k<<<3072, 256, 0, stream>>>(wq, wk, wv, wqkv_hi, wqkv_lo);
  conv_split_k<<<2048, 256, 0, stream>>>(wo, wo_hi, wo_lo);
  conv_w13_k<<<65536, 256, 0, stream>>>(w1, w3, w13b);
  conv_bf_k<<<32768, 256, 0, stream>>>(w2, w2b);
  rope_tab_k<<<256, 256, 0, stream>>>(ctab, stab);

  // attention path (split bf16)
  rmsnorm_k<<<2048, 256, 0, stream>>>(hidden, ln1, x_hi, x_lo, nullptr, nullptr);
  gemm_k<0, true><<<dim3(24, 16), 256, 0, stream>>>(x_hi, x_lo, wqkv_hi, wqkv_lo, 2048, 3072,
                                                    qkvf, nullptr, nullptr, nullptr, 0, nullptr, nullptr);
  rope_k<<<dim3(2048, 48), 64, 0, stream>>>(qkvf, ctab, stab, q_hi, q_lo, k_hi, k_lo, v_hi, v_lo);
  vtrans_k<<<dim3(32, 8), 256, 0, stream>>>(v_hi, v_lo, vth, vtl);
  attn_k<<<dim3(128, 32), 64, 0, stream>>>(q_hi, q_lo, k_hi, k_lo, vth, vtl, o_hi, o_lo);
  gemm_k<1, true><<<dim3(16, 16), 256, 0, stream>>>(o_hi, o_lo, wo_hi, wo_lo, 2048, 2048,
                                                    hidf, nullptr, hidden, nullptr, 0, nullptr, nullptr);

  // MoE
  rmsnorm_k<<<2048, 256, 0, stream>>>(hidf, ln2, nullptr, nullptr, xmf, xmbf);
  moe_init_k<<<20, 256, 0, stream>>>(cnt, fill, tokof);
  router_k<<<2048, 64, 0, stream>>>(xmf, gw, sel, topw, cnt);
  moe_base_k<<<1, 64, 0, stream>>>(cnt, mbase);
  slot_assign_k<<<8, 256, 0, stream>>>(sel, topw, mbase, fill, tokof, wgtof);
  gather_k<<<5120, 256, 0, stream>>>(tokof, xmbf, xg);
  gemm_k<2, false><<<dim3(64, 40), 256, 0, stream>>>(xg, nullptr, w13b, nullptr, 2048, 8192,
                                                     nullptr, h13, nullptr, mbase, 8192L * 2048,
                                                     nullptr, nullptr);
  silu_k<<<10240, 256, 0, stream>>>(h13, hpr);
  hipMemcpyAsync(out, hidf, 2048UL * 2048 * 4, hipMemcpyDeviceToDevice, stream);
  gemm_k<3, false><<<dim3(16, 40), 256, 0, stream>>>(hpr, nullptr, w2b, nullptr, 4096, 2048,
                                                     out, nullptr, nullptr, mbase, 2048L * 4096,
                                                     tokof, wgtof);
}